// Round 4
// baseline (475.372 us; speedup 1.0000x reference)
//
#include <hip/hip_runtime.h>

// MultiHeadAttention MI355X (gfx950)
// B=2, S=2048, H=2048, NH=16, HD=128. fp32 in/out, bf16 MFMA compute.
// Pipeline: cast -> qkv proj GEMM (merged launch; V transposed out, Q pre-scaled
// by 1/sqrt(HD)*log2(e)) -> flash attention (exp2 softmax) -> out GEMM.
// R9: flash uses a delayed-PV pipeline: iter kb = QK^T(kb) -> PV(kb-1) -> softmax(kb).
// PV consumes P-fragments read from LDS LAST iteration (round-trip latency off the
// critical path); both 32-MFMA clusters adjacent (setprio-wrapped); V single-buffered
// with a full iteration of in-flight slack. 3 barriers/tile, 67.6KB LDS, 2 blk/CU.

typedef __bf16 bf16_t;
typedef __bf16 bf16x8 __attribute__((ext_vector_type(8)));
typedef float  f32x4  __attribute__((ext_vector_type(4)));

#define DEVI __device__ __forceinline__

DEVI void async_copy16(const void* gsrc, void* ldst) {
  __builtin_amdgcn_global_load_lds(
      (const __attribute__((address_space(1))) unsigned int*)gsrc,
      (__attribute__((address_space(3))) unsigned int*)ldst, 16, 0, 0);
}

constexpr int Bc = 2, Sc = 2048, Hc = 2048, NHc = 16, HDc = 128;
// 1/sqrt(128) * log2(e): Q pre-scale so flash softmax runs in exp2 domain.
constexpr float SCALE_LOG2E = 0.12751744550358464f;
constexpr int PSTR = 72;  // P row stride (bf16): 72*2=144B=9*16 -> rows 16B-aligned

// ---------------------------------------------------------------- casts (merged launches)
DEVI void cast_body(const float* __restrict__ in, bf16_t* __restrict__ out) {
  int i = (blockIdx.x * 256 + threadIdx.x) * 8;
  float4 f0 = *(const float4*)(in + i);
  float4 f1 = *(const float4*)(in + i + 4);
  union { bf16_t h[8]; uint4 u; } o;
  o.h[0] = (bf16_t)f0.x; o.h[1] = (bf16_t)f0.y;
  o.h[2] = (bf16_t)f0.z; o.h[3] = (bf16_t)f0.w;
  o.h[4] = (bf16_t)f1.x; o.h[5] = (bf16_t)f1.y;
  o.h[6] = (bf16_t)f1.z; o.h[7] = (bf16_t)f1.w;
  *(uint4*)(out + i) = o.u;
}

__global__ void cast3(const float* __restrict__ a, const float* __restrict__ b,
                      const float* __restrict__ c, bf16_t* __restrict__ oa,
                      bf16_t* __restrict__ ob, bf16_t* __restrict__ oc) {
  const float* src = blockIdx.y == 0 ? a : blockIdx.y == 1 ? b : c;
  bf16_t* dst = blockIdx.y == 0 ? oa : blockIdx.y == 1 ? ob : oc;
  cast_body(src, dst);
}

__global__ void cast4(const float* __restrict__ a, const float* __restrict__ b,
                      const float* __restrict__ c, const float* __restrict__ d,
                      bf16_t* __restrict__ oa, bf16_t* __restrict__ ob,
                      bf16_t* __restrict__ oc, bf16_t* __restrict__ od) {
  const float* src = blockIdx.y == 0 ? a : blockIdx.y == 1 ? b
                   : blockIdx.y == 2 ? c : d;
  bf16_t* dst = blockIdx.y == 0 ? oa : blockIdx.y == 1 ? ob
              : blockIdx.y == 2 ? oc : od;
  cast_body(src, dst);
}

// ---------------------------------------------------------------- bt-GEMM body
// C[m,n] = (sum_k A[m,k]*Bw[n,k] + bias[n]) * scale.  A: MxK bf16 rm, Bw: NxK bf16 rm.
// out_mode 0: bf16 row-major MxN. 1: bf16 transposed to (B,NH,HD,S). 2: f32 MxN.
// BM=256 BN=128 BK=64, 512 threads, 8 waves as 2M x 4N (per-wave 128 x 32).
// 3-slot LDS ring (compute kt from slot kt%3, kt+1 resident, kt+2 streaming).
// Per K-tile: entry {vmcnt(6); barrier} then 2 phases of
//   {ds_read frags || issue 3 stage loads; barrier; lgkmcnt(0); sched_barrier;
//    setprio(1); 16 MFMA; setprio(0); barrier}.
template <int M, int N, int K>
DEVI void gemm_body(const bf16_t* __restrict__ A, const bf16_t* __restrict__ Bw,
                    const float* __restrict__ bias, void* __restrict__ Cout,
                    float scale, int out_mode) {
  constexpr int BM = 256, BN = 128, BK = 64;
  constexpr int NT = K / BK;                 // 32
  constexpr int SLOT = (BM + BN) * BK;       // 24576 elems = 48KB
  __shared__ __align__(16) bf16_t lds[3 * SLOT];  // 144KB -> 1 block/CU

  const int tid = threadIdx.x;
  const int lane = tid & 63;
  const int wave = tid >> 6;                 // 0..7
  // XCD-aware bijective swizzle (8 XCDs, 256 blocks): XCD x owns logical tiles
  // [x*32, x*32+32) -> 2 B-panels per XCD stay L2-resident.
  const int lid = (blockIdx.x & 7) * 32 + (blockIdx.x >> 3);
  const int bm = lid & (M / BM - 1);
  const int bn = lid / (M / BM);
  const int wm = wave >> 2, wn = wave & 3;   // 2M x 4N
  const int quad = lane >> 4, l15 = lane & 15;

  // Staging map. A: 32 segs of (8 rows x 64 cols) = 1KB; wave stages segs wave*4+i.
  // B: 16 segs; wave stages segs wave*2+i. XOR-swizzled global source, linear LDS.
  const bf16_t* Abase = A + (size_t)bm * BM * K;
  const bf16_t* Bbase = Bw + (size_t)bn * BN * K;
  const bf16_t* asrc0; const bf16_t* asrc1; const bf16_t* asrc2; const bf16_t* asrc3;
  const bf16_t* bsrc0; const bf16_t* bsrc1;
  int aoff0, aoff1, aoff2, aoff3, boff0, boff1;
  {
    int i0 = wave * 4;
    int r0 = i0 * 8 + (lane >> 3);       aoff0 = i0 * 512;
    int r1 = (i0 + 1) * 8 + (lane >> 3); aoff1 = (i0 + 1) * 512;
    int r2 = (i0 + 2) * 8 + (lane >> 3); aoff2 = (i0 + 2) * 512;
    int r3 = (i0 + 3) * 8 + (lane >> 3); aoff3 = (i0 + 3) * 512;
    asrc0 = Abase + (size_t)r0 * K + (((lane & 7) ^ (r0 & 7)) * 8);
    asrc1 = Abase + (size_t)r1 * K + (((lane & 7) ^ (r1 & 7)) * 8);
    asrc2 = Abase + (size_t)r2 * K + (((lane & 7) ^ (r2 & 7)) * 8);
    asrc3 = Abase + (size_t)r3 * K + (((lane & 7) ^ (r3 & 7)) * 8);
    int j0 = wave * 2;
    int s0 = j0 * 8 + (lane >> 3);       boff0 = BM * BK + j0 * 512;
    int s1 = (j0 + 1) * 8 + (lane >> 3); boff1 = BM * BK + (j0 + 1) * 512;
    bsrc0 = Bbase + (size_t)s0 * K + (((lane & 7) ^ (s0 & 7)) * 8);
    bsrc1 = Bbase + (size_t)s1 * K + (((lane & 7) ^ (s1 & 7)) * 8);
  }

  f32x4 zero4 = {0.f, 0.f, 0.f, 0.f};
  f32x4 acc[8][2];
#pragma unroll
  for (int i = 0; i < 8; ++i)
#pragma unroll
    for (int j = 0; j < 2; ++j) acc[i][j] = zero4;

  auto stage_half0 = [&](int kt) {
    bf16_t* slot = lds + (kt % 3) * SLOT;
    int k0 = kt * BK;
    async_copy16(asrc0 + k0, slot + aoff0);
    async_copy16(asrc1 + k0, slot + aoff1);
    async_copy16(bsrc0 + k0, slot + boff0);
  };
  auto stage_half1 = [&](int kt) {
    bf16_t* slot = lds + (kt % 3) * SLOT;
    int k0 = kt * BK;
    async_copy16(asrc2 + k0, slot + aoff2);
    async_copy16(asrc3 + k0, slot + aoff3);
    async_copy16(bsrc1 + k0, slot + boff1);
  };

  // prologue: tiles 0 and 1 in flight (12 loads/thread)
  stage_half0(0); stage_half1(0);
  stage_half0(1); stage_half1(1);

  for (int kt = 0; kt < NT; ++kt) {
    // tile kt must have landed; tile kt+1's 6 loads may remain outstanding.
    if (kt + 1 < NT) {
      asm volatile("s_waitcnt vmcnt(6)" ::: "memory");
    } else {
      asm volatile("s_waitcnt vmcnt(0)" ::: "memory");
    }
    __builtin_amdgcn_s_barrier();
    asm volatile("" ::: "memory");

    const bf16_t* As = lds + (kt % 3) * SLOT;
    const bf16_t* Bs = As + BM * BK;
    const bool do_stage = (kt + 2 < NT);

    bf16x8 afr[4][2], bfr[2][2];

    // ---- phase 0: frags A m=0..3 (+ all B), stage half0(kt+2), MFMA m=0..3
#pragma unroll
    for (int m = 0; m < 4; ++m) {
      int ar = wm * 128 + m * 16 + l15;
#pragma unroll
      for (int ks = 0; ks < 2; ++ks)
        afr[m][ks] = *(const bf16x8*)(As + ar * 64 + (((ks * 4 + quad) ^ (ar & 7)) * 8));
    }
#pragma unroll
    for (int n = 0; n < 2; ++n) {
      int br = wn * 32 + n * 16 + l15;
#pragma unroll
      for (int ks = 0; ks < 2; ++ks)
        bfr[n][ks] = *(const bf16x8*)(Bs + br * 64 + (((ks * 4 + quad) ^ (br & 7)) * 8));
    }
    if (do_stage) stage_half0(kt + 2);
    __builtin_amdgcn_s_barrier();
    asm volatile("s_waitcnt lgkmcnt(0)" ::: "memory");
    __builtin_amdgcn_sched_barrier(0);
    __builtin_amdgcn_s_setprio(1);
#pragma unroll
    for (int m = 0; m < 4; ++m)
#pragma unroll
      for (int n = 0; n < 2; ++n)
#pragma unroll
        for (int ks = 0; ks < 2; ++ks)
          acc[m][n] = __builtin_amdgcn_mfma_f32_16x16x32_bf16(
              afr[m][ks], bfr[n][ks], acc[m][n], 0, 0, 0);
    __builtin_amdgcn_s_setprio(0);
    __builtin_amdgcn_s_barrier();
    asm volatile("" ::: "memory");

    // ---- phase 1: frags A m=4..7, stage half1(kt+2), MFMA m=4..7
#pragma unroll
    for (int m = 0; m < 4; ++m) {
      int ar = wm * 128 + (m + 4) * 16 + l15;
#pragma unroll
      for (int ks = 0; ks < 2; ++ks)
        afr[m][ks] = *(const bf16x8*)(As + ar * 64 + (((ks * 4 + quad) ^ (ar & 7)) * 8));
    }
    if (do_stage) stage_half1(kt + 2);
    __builtin_amdgcn_s_barrier();
    asm volatile("s_waitcnt lgkmcnt(0)" ::: "memory");
    __builtin_amdgcn_sched_barrier(0);
    __builtin_amdgcn_s_setprio(1);
#pragma unroll
    for (int m = 0; m < 4; ++m)
#pragma unroll
      for (int n = 0; n < 2; ++n)
#pragma unroll
        for (int ks = 0; ks < 2; ++ks)
          acc[m + 4][n] = __builtin_amdgcn_mfma_f32_16x16x32_bf16(
              afr[m][ks], bfr[n][ks], acc[m + 4][n], 0, 0, 0);
    __builtin_amdgcn_s_setprio(0);
    // no closing barrier: next tile's entry {vmcnt; barrier} provides it.
  }

  float bv2[2];
#pragma unroll
  for (int n = 0; n < 2; ++n) bv2[n] = bias[bn * BN + wn * 32 + n * 16 + l15];

#pragma unroll
  for (int m = 0; m < 8; ++m) {
    const int rbase = bm * BM + wm * 128 + m * 16 + quad * 4;
#pragma unroll
    for (int n = 0; n < 2; ++n) {
      const int col = bn * BN + wn * 32 + n * 16 + l15;
      if (out_mode == 0) {
        bf16_t* C = (bf16_t*)Cout;
#pragma unroll
        for (int r = 0; r < 4; ++r)
          C[(size_t)(rbase + r) * N + col] = (bf16_t)((acc[m][n][r] + bv2[n]) * scale);
      } else if (out_mode == 2) {
        float* C = (float*)Cout;
#pragma unroll
        for (int r = 0; r < 4; ++r)
          C[(size_t)(rbase + r) * N + col] = acc[m][n][r] + bv2[n];
      } else {  // transposed bf16 -> (B, NH, HD, S)
        bf16_t* C = (bf16_t*)Cout;
        const int bb = rbase >> 11;
        const int s0 = rbase & (Sc - 1);
        const int h = col >> 7, d = col & (HDc - 1);
        union { bf16_t h4[4]; uint2 u; } o;
#pragma unroll
        for (int r = 0; r < 4; ++r) o.h4[r] = (bf16_t)(acc[m][n][r] + bv2[n]);
        *(uint2*)(C + (((size_t)(bb * NHc + h) * HDc + d) * Sc + s0)) = o.u;
      }
    }
  }
}

// merged Q/K/V projection: blockIdx.y selects which. Saves 2 launch gaps.
__global__ __launch_bounds__(512, 2) void qkv_proj(
    const bf16_t* __restrict__ Xq, const bf16_t* __restrict__ Xk,
    const bf16_t* __restrict__ Xv, const bf16_t* __restrict__ Wq,
    const bf16_t* __restrict__ Wk, const bf16_t* __restrict__ Wv,
    const float* __restrict__ bq, const float* __restrict__ bk,
    const float* __restrict__ bv, bf16_t* __restrict__ q,
    bf16_t* __restrict__ k, bf16_t* __restrict__ vt) {
  const int p = blockIdx.y;
  const bf16_t* A = p == 0 ? Xq : p == 1 ? Xk : Xv;
  const bf16_t* W = p == 0 ? Wq : p == 1 ? Wk : Wv;
  const float* bi = p == 0 ? bq : p == 1 ? bk : bv;
  void* out = p == 0 ? (void*)q : p == 1 ? (void*)k : (void*)vt;
  gemm_body<4096, 2048, 2048>(A, W, bi, out, p == 0 ? SCALE_LOG2E : 1.0f,
                              p == 2 ? 1 : 0);
}

__global__ __launch_bounds__(512, 2) void o_proj(
    const bf16_t* __restrict__ A, const bf16_t* __restrict__ W,
    const float* __restrict__ bi, float* __restrict__ out) {
  gemm_body<4096, 2048, 2048>(A, W, bi, out, 1.0f, 2);
}

// ---------------------------------------------------------------- flash attention
// grid = B*NH*(S/128) = 512; block = 256 (4 waves); 2 blocks/CU.
// KV tiles of 64 keys -> 32 iterations. Wave w owns q-rows [32w,32w+32).
// LDS 67584B: K0 64x128 | K1 64x128 | Vt 128x64 | P 4 x 32 x PSTR.
// Delayed-PV pipeline: iter kb = {K-wait; QK^T(kb); V-wait; PV(kb-1) from pf regs
// read LAST iter; softmax(kb) -> P -> LDS -> pf}. V single-buffered with a full
// iteration of in-flight slack; K double-buffered. setprio wraps both MFMA
// clusters. Per-wave load FIFO traced: entry vmcnt(8) (4 at kb=0/31),
// pre-PV vmcnt(4) (0 at kb=31). Tile 31's PV runs post-loop.
__global__ __launch_bounds__(256, 2) void flash_attn(const bf16_t* __restrict__ Q,
                                                     const bf16_t* __restrict__ Kg,
                                                     const bf16_t* __restrict__ Vt,
                                                     bf16_t* __restrict__ ctx) {
  __shared__ __align__(16) bf16_t smem[2 * 64 * 128 + 128 * 64 + 4 * 32 * PSTR];
  bf16_t* Ks0 = smem;             // K[even] 64x128
  bf16_t* Ks1 = smem + 8192;      // K[odd]  64x128
  bf16_t* Vs = smem + 16384;      // 128 hd x 64 keys (transposed V)
  bf16_t* Ps = smem + 24576;      // per-wave 32 x PSTR

  const int tid = threadIdx.x, lane = tid & 63, wave = tid >> 6;
  const int quad = lane >> 4, l15 = lane & 15;
  const int bid = blockIdx.x;
  const int qt = bid & 15, h = (bid >> 4) & 15, b = bid >> 8;

  bf16_t* Pw = Ps + wave * (32 * PSTR);

  // Q fragments, held in registers for all 32 kv-tiles
  bf16x8 qf[2][4];
#pragma unroll
  for (int mt = 0; mt < 2; ++mt) {
    int grow = b * Sc + qt * 128 + wave * 32 + mt * 16 + l15;
    const bf16_t* qp = Q + (size_t)grow * Hc + h * HDc;
#pragma unroll
    for (int kc = 0; kc < 4; ++kc) qf[mt][kc] = *(const bf16x8*)(qp + kc * 32 + quad * 8);
  }

  f32x4 zero4 = {0.f, 0.f, 0.f, 0.f};
  f32x4 o[2][8];
#pragma unroll
  for (int mt = 0; mt < 2; ++mt)
#pragma unroll
    for (int dt = 0; dt < 8; ++dt) o[mt][dt] = zero4;
  float mrow[2][4], lpart[2][4];
#pragma unroll
  for (int mt = 0; mt < 2; ++mt)
#pragma unroll
    for (int r = 0; r < 4; ++r) { mrow[mt][r] = -1e30f; lpart[mt][r] = 0.f; }

  bf16x8 pf[2][2];  // P(kb) A-fragments, produced at iter kb, consumed at kb+1

  // staging maps (XOR-swizzled global src, linear LDS dst)
  int kr_[4], kc_[4], vr_[4], vc_[4];
#pragma unroll
  for (int i = 0; i < 4; ++i) {
    int s = wave * 4 + i;
    kr_[i] = s * 4 + quad;        kc_[i] = l15 ^ (kr_[i] & 7);
    vr_[i] = s * 8 + (lane >> 3); vc_[i] = (lane & 7) ^ (vr_[i] & 7);
  }
  const bf16_t* Kbase = Kg + (size_t)b * Sc * Hc + h * HDc;
  const bf16_t* Vbase = Vt + (size_t)(b * NHc + h) * HDc * Sc;

  auto stageK = [&](int kb, bf16_t* dst) {
#pragma unroll
    for (int i = 0; i < 4; ++i)
      async_copy16(Kbase + (size_t)(kb * 64 + kr_[i]) * Hc + kc_[i] * 8,
                   dst + (wave * 4 + i) * 512);
  };
  auto stageV = [&](int kb) {
#pragma unroll
    for (int i = 0; i < 4; ++i)
      async_copy16(Vbase + (size_t)vr_[i] * Sc + kb * 64 + vc_[i] * 8,
                   Vs + (wave * 4 + i) * 512);
  };

  // prologue FIFO: K0(4), K1(4). V[0] is staged at the END of iter 0.
  stageK(0, Ks0);
  stageK(1, Ks1);

  for (int kb = 0; kb < 32; ++kb) {
    bf16_t* Kcur = (kb & 1) ? Ks1 : Ks0;

    // entry: K[kb] landed.
    // FIFO: kb=0:[K0,K1]; 1<=kb<=30:[K[kb],V[kb-1],K[kb+1]]; kb=31:[K31,V30].
    if (kb == 0 || kb == 31) asm volatile("s_waitcnt vmcnt(4)" ::: "memory");
    else                     asm volatile("s_waitcnt vmcnt(8)" ::: "memory");
    __builtin_amdgcn_s_barrier();
    asm volatile("" ::: "memory");

    // ---- S = Q K^T(kb)  (kc outer -> 8 independent MFMA chains)
    f32x4 sf[2][4];
#pragma unroll
    for (int mt = 0; mt < 2; ++mt)
#pragma unroll
      for (int nt = 0; nt < 4; ++nt) sf[mt][nt] = zero4;
    __builtin_amdgcn_s_setprio(1);
#pragma unroll
    for (int kc = 0; kc < 4; ++kc)
#pragma unroll
      for (int nt = 0; nt < 4; ++nt) {
        int kr = nt * 16 + l15;
        bf16x8 kf = *(const bf16x8*)(Kcur + kr * 128 + (((kc * 4 + quad) ^ (kr & 7)) * 8));
        sf[0][nt] = __builtin_amdgcn_mfma_f32_16x16x32_bf16(qf[0][kc], kf, sf[0][nt], 0, 0, 0);
        sf[1][nt] = __builtin_amdgcn_mfma_f32_16x16x32_bf16(qf[1][kc], kf, sf[1][nt], 0, 0, 0);
      }
    __builtin_amdgcn_s_setprio(0);

    // ---- PV(kb-1): pf from last iter (regs), Vs = V[kb-1]
    if (kb > 0) {
      if (kb == 31) asm volatile("s_waitcnt vmcnt(0)" ::: "memory");
      else          asm volatile("s_waitcnt vmcnt(4)" ::: "memory");
      __builtin_amdgcn_s_barrier();
      asm volatile("" ::: "memory");
      __builtin_amdgcn_s_setprio(1);
#pragma unroll
      for (int kc = 0; kc < 2; ++kc)
#pragma unroll
        for (int dt = 0; dt < 8; ++dt) {
          int vr = dt * 16 + l15;
          bf16x8 vf = *(const bf16x8*)(Vs + vr * 64 + (((kc * 4 + quad) ^ (vr & 7)) * 8));
          o[0][dt] = __builtin_amdgcn_mfma_f32_16x16x32_bf16(pf[0][kc], vf, o[0][dt], 0, 0, 0);
          o[1][dt] = __builtin_amdgcn_mfma_f32_16x16x32_bf16(pf[1][kc], vf, o[1][dt], 0, 0, 0);
        }
      __builtin_amdgcn_s_setprio(0);
    }

    // ---- online softmax(kb), exp2 domain. Rescale of o is AFTER PV(kb-1): correct.
    float mx[2][4];
    bool need = false;
#pragma unroll
    for (int mt = 0; mt < 2; ++mt)
#pragma unroll
      for (int r = 0; r < 4; ++r) {
        float m0 = fmaxf(fmaxf(sf[mt][0][r], sf[mt][1][r]),
                         fmaxf(sf[mt][2][r], sf[mt][3][r]));
#pragma unroll
        for (int off = 1; off < 16; off <<= 1) m0 = fmaxf(m0, __shfl_xor(m0, off));
        mx[mt][r] = m0;
        need = need || (m0 > mrow[mt][r] + 8.0f);
      }
    if (__any(need)) {  // rare after the first tiles: full rescale
#pragma unroll
      for (int mt = 0; mt < 2; ++mt)
#pragma unroll
        for (int r = 0; r < 4; ++r) {
          float mnew = fmaxf(mrow[mt][r], mx[mt][r]);
          float alpha = __builtin_amdgcn_exp2f(mrow[mt][r] - mnew);
          mrow[mt][r] = mnew;
          lpart[mt][r] *= alpha;
#pragma unroll
          for (int dt = 0; dt < 8; ++dt) o[mt][dt][r] *= alpha;
        }
    }
#pragma unroll
    for (int mt = 0; mt < 2; ++mt)
#pragma unroll
      for (int r = 0; r < 4; ++r) {
        float p0 = __builtin_amdgcn_exp2f(sf[mt][0][r] - mrow[mt][r]);
        float p1 = __builtin_amdgcn_exp2f(sf[mt][1][r] - mrow[mt][r]);
        float p2 = __builtin_amdgcn_exp2f(sf[mt][2][r] - mrow[mt][r]);
        float p3 = __builtin_amdgcn_exp2f(sf[mt][3][r] - mrow[mt][r]);
        sf[mt][0][r] = p0; sf[mt][1][r] = p1;
        sf[mt][2][r] = p2; sf[mt][3][r] = p3;
        lpart[mt][r] += (p0 + p1) + (p2 + p3);  // per-lane partial; reduce at epilogue
      }

    // P: C-layout regs -> LDS bf16 (wave-private, rows 16B-aligned) -> A-layout frags
#pragma unroll
    for (int mt = 0; mt < 2; ++mt)
#pragma unroll
      for (int nt = 0; nt < 4; ++nt)
#pragma unroll
        for (int r = 0; r < 4; ++r)
          Pw[(mt * 16 + quad * 4 + r) * PSTR + nt * 16 + l15] = (bf16_t)sf[mt][nt][r];

#pragma unroll
    for (int mt = 0; mt < 2; ++mt) {
      const bf16_t* pr = Pw + (mt * 16 + l15) * PSTR;
#pragma unroll
      for (int kc = 0; kc < 2; ++kc)
        pf[mt][kc] = *(const bf16x8*)(pr + kc * 32 + quad * 8);
    }

    // all waves done reading Vs (PV(kb-1)) and Kcur (QK^T(kb)) -> restage both
    __builtin_amdgcn_s_barrier();
    asm volatile("" ::: "memory");
    stageV(kb);                              // consumed at iter kb+1 (or post-loop)
    if (kb + 2 < 32) stageK(kb + 2, Kcur);   // K[kb+2] lives in kb's buffer
  }

  // ---- post-loop: PV(31)
  asm volatile("s_waitcnt vmcnt(0)" ::: "memory");
  __builtin_amdgcn_s_barrier();
  asm volatile("" ::: "memory");
#pragma unroll
  for (int kc = 0; kc < 2; ++kc)
#pragma unroll
    for (int dt = 0; dt < 8; ++dt) {
      int vr = dt * 16 + l15;
      bf16x8 vf = *(const bf16x8*)(Vs + vr * 64 + (((kc * 4 + quad) ^ (vr & 7)) * 8));
      o[0][dt] = __builtin_amdgcn_mfma_f32_16x16x32_bf16(pf[0][kc], vf, o[0][dt], 0, 0, 0);
      o[1][dt] = __builtin_amdgcn_mfma_f32_16x16x32_bf16(pf[1][kc], vf, o[1][dt], 0, 0, 0);
    }

  // epilogue: reduce lpart across the 16-lane row group, then O -> smem overlay
  __syncthreads();  // everyone done with Ks/Vs before overlay
  bf16_t* Ow = smem + wave * 4096;  // 32 rows x 128 cols
#pragma unroll
  for (int mt = 0; mt < 2; ++mt) {
    float rinv[4];
#pragma unroll
    for (int r = 0; r < 4; ++r) {
      float l = lpart[mt][r];
#pragma unroll
      for (int off = 1; off < 16; off <<= 1) l += __shfl_xor(l, off);
      rinv[r] = 1.f / l;
    }
#pragma unroll
    for (int dt = 0; dt < 8; ++dt)
#pragma unroll
      for (int r = 0; r < 4; ++r)
        Ow[(mt * 16 + quad * 4 + r) * 128 + dt * 16 + l15] = (bf16_t)(o[mt][dt][r] * rinv[r]);
  }
#pragma unroll
  for (int r = 0; r < 32; ++r) {
    unsigned v = *(const unsigned*)(Ow + r * 128 + lane * 2);
    int grow = b * Sc + qt * 128 + wave * 32 + r;
    *(unsigned*)(ctx + (size_t)grow * Hc + h * HDc + lane * 2) = v;
  }
}

// ---------------------------------------------------------------- launch
extern "C" void kernel_launch(void* const* d_in, const int* in_sizes, int n_in,
                              void* d_out, int out_size, void* d_ws, size_t ws_size,
                              hipStream_t stream) {
  const float* query = (const float*)d_in[0];
  const float* key_i = (const float*)d_in[1];
  const float* value = (const float*)d_in[2];
  const float* Wq = (const float*)d_in[3];
  const float* bq = (const float*)d_in[4];
  const float* Wk = (const float*)d_in[5];
  const float* bk = (const float*)d_in[6];
  const float* Wv = (const float*)d_in[7];
  const float* bv = (const float*)d_in[8];
  const float* Wo = (const float*)d_in[9];
  const float* bo = (const float*)d_in[10];

  const size_t XE = (size_t)Bc * Sc * Hc;  // 8,388,608
  const size_t WE = (size_t)Hc * Hc;       // 4,194,304
  const size_t need = 6 * XE * 2 + 4 * WE * 2;  // 128 MB
  if (ws_size < need) return;

  char* ws = (char*)d_ws;
  size_t off = 0;
  auto alloc = [&](size_t bytes) {
    char* p = ws + off;
    off += (bytes + 255) & ~(size_t)255;
    return p;
  };
  bf16_t* Xq = (bf16_t*)alloc(XE * 2);
  bf16_t* Xk = (bf16_t*)alloc(XE * 2);
  bf16_t* Xv = (bf16_t*)alloc(XE * 2);
  bf16_t* Wqb = (bf16_t*)alloc(WE * 2);
  bf16_t* Wkb = (bf16_t*)alloc(WE * 2);
  bf16_t* Wvb = (bf16_t*)alloc(WE * 2);
  bf16_t* Wob = (bf16_t*)alloc(WE * 2);
  bf16_t* qb = (bf16_t*)alloc(XE * 2);
  bf16_t* kb = (bf16_t*)alloc(XE * 2);
  bf16_t* vtb = (bf16_t*)alloc(XE * 2);
  bf16_t* ctxb = Xq;  // Xq dead after q-projection; reuse for ctx

  cast3<<<dim3((unsigned)(XE / 2048), 3), 256, 0, stream>>>(query, key_i, value, Xq, Xk, Xv);
  cast4<<<dim3((unsigned)(WE / 2048), 4), 256, 0, stream>>>(Wq, Wk, Wv, Wo, Wqb, Wkb, Wvb, Wob);

  qkv_proj<<<dim3(256, 3), 512, 0, stream>>>(Xq, Xk, Xv, Wqb, Wkb, Wvb,
                                             bq, bk, bv, qb, kb, vtb);

  flash_attn<<<512, 256, 0, stream>>>(qb, kb, vtb, ctxb);

  o_proj<<<256, 512, 0, stream>>>(ctxb, Wob, bo, (float*)d_out);
}

// Round 5
// 418.593 us; speedup vs baseline: 1.1356x; 1.1356x over previous
//
#include <hip/hip_runtime.h>

// MultiHeadAttention MI355X (gfx950)
// B=2, S=2048, H=2048, NH=16, HD=128. fp32 in/out, bf16 MFMA compute.
// Pipeline: cast -> qkv proj GEMM (merged launch; V transposed out, Q pre-scaled
// by 1/sqrt(HD)*log2(e)) -> flash attention (exp2 softmax) -> out GEMM.
// R10: flash reverted to the R7 schedule (K dbuf, split counted vmcnt waits,
// V-wait after QK^T+softmax; R9's delayed-PV regressed and is dropped).
// New: shuffle-free softmax common path -- the 16-lane max-reduce (32 ds_swizzle
// per tile, 4-deep dep chain) runs ONLY when a lane-local max exceeds mrow+8
// (exact test since mrow is row-uniform). Common path: 3 fmax + 1 cmp per
// row-value, zero cross-lane ops. GEMM = R6/R7 structure (best measured total).

typedef __bf16 bf16_t;
typedef __bf16 bf16x8 __attribute__((ext_vector_type(8)));
typedef float  f32x4  __attribute__((ext_vector_type(4)));

#define DEVI __device__ __forceinline__

DEVI void async_copy16(const void* gsrc, void* ldst) {
  __builtin_amdgcn_global_load_lds(
      (const __attribute__((address_space(1))) unsigned int*)gsrc,
      (__attribute__((address_space(3))) unsigned int*)ldst, 16, 0, 0);
}

constexpr int Bc = 2, Sc = 2048, Hc = 2048, NHc = 16, HDc = 128;
// 1/sqrt(128) * log2(e): Q pre-scale so flash softmax runs in exp2 domain.
constexpr float SCALE_LOG2E = 0.12751744550358464f;
constexpr int PSTR = 72;  // P row stride (bf16): 72*2=144B=9*16 -> rows 16B-aligned

// ---------------------------------------------------------------- casts (merged launches)
DEVI void cast_body(const float* __restrict__ in, bf16_t* __restrict__ out) {
  int i = (blockIdx.x * 256 + threadIdx.x) * 8;
  float4 f0 = *(const float4*)(in + i);
  float4 f1 = *(const float4*)(in + i + 4);
  union { bf16_t h[8]; uint4 u; } o;
  o.h[0] = (bf16_t)f0.x; o.h[1] = (bf16_t)f0.y;
  o.h[2] = (bf16_t)f0.z; o.h[3] = (bf16_t)f0.w;
  o.h[4] = (bf16_t)f1.x; o.h[5] = (bf16_t)f1.y;
  o.h[6] = (bf16_t)f1.z; o.h[7] = (bf16_t)f1.w;
  *(uint4*)(out + i) = o.u;
}

__global__ void cast3(const float* __restrict__ a, const float* __restrict__ b,
                      const float* __restrict__ c, bf16_t* __restrict__ oa,
                      bf16_t* __restrict__ ob, bf16_t* __restrict__ oc) {
  const float* src = blockIdx.y == 0 ? a : blockIdx.y == 1 ? b : c;
  bf16_t* dst = blockIdx.y == 0 ? oa : blockIdx.y == 1 ? ob : oc;
  cast_body(src, dst);
}

__global__ void cast4(const float* __restrict__ a, const float* __restrict__ b,
                      const float* __restrict__ c, const float* __restrict__ d,
                      bf16_t* __restrict__ oa, bf16_t* __restrict__ ob,
                      bf16_t* __restrict__ oc, bf16_t* __restrict__ od) {
  const float* src = blockIdx.y == 0 ? a : blockIdx.y == 1 ? b
                   : blockIdx.y == 2 ? c : d;
  bf16_t* dst = blockIdx.y == 0 ? oa : blockIdx.y == 1 ? ob
              : blockIdx.y == 2 ? oc : od;
  cast_body(src, dst);
}

// ---------------------------------------------------------------- bt-GEMM body
// C[m,n] = (sum_k A[m,k]*Bw[n,k] + bias[n]) * scale.  A: MxK bf16 rm, Bw: NxK bf16 rm.
// out_mode 0: bf16 row-major MxN. 1: bf16 transposed to (B,NH,HD,S). 2: f32 MxN.
// BM=256 BN=128 BK=64, 512 threads (8 waves as 4M x 2N, 64x64/wave, acc[4][4]).
// 3-slot LDS ring, counted s_waitcnt vmcnt(6), raw s_barrier (R6 structure).
template <int M, int N, int K>
DEVI void gemm_body(const bf16_t* __restrict__ A, const bf16_t* __restrict__ Bw,
                    const float* __restrict__ bias, void* __restrict__ Cout,
                    float scale, int out_mode) {
  constexpr int BM = 256, BN = 128, BK = 64;
  constexpr int NT = K / BK;                 // 32
  constexpr int SLOT = (BM + BN) * BK;       // 24576 elems = 48KB
  __shared__ __align__(16) bf16_t lds[3 * SLOT];  // 144KB -> 1 block/CU

  const int tid = threadIdx.x;
  const int lane = tid & 63;
  const int wave = tid >> 6;                 // 0..7
  const int bm = blockIdx.x & (M / BM - 1);
  const int bn = blockIdx.x / (M / BM);
  const int wm = wave >> 1, wn = wave & 1;
  const int quad = lane >> 4, l15 = lane & 15;

  const bf16_t* Abase = A + (size_t)bm * BM * K;
  const bf16_t* Bbase = Bw + (size_t)bn * BN * K;
  const bf16_t* asrc0; const bf16_t* asrc1; const bf16_t* asrc2; const bf16_t* asrc3;
  const bf16_t* bsrc0; const bf16_t* bsrc1;
  int aoff0, aoff1, aoff2, aoff3, boff0, boff1;
  {
    int i0 = wave * 4;
    int r0 = i0 * 8 + (lane >> 3);       aoff0 = i0 * 512;
    int r1 = (i0 + 1) * 8 + (lane >> 3); aoff1 = (i0 + 1) * 512;
    int r2 = (i0 + 2) * 8 + (lane >> 3); aoff2 = (i0 + 2) * 512;
    int r3 = (i0 + 3) * 8 + (lane >> 3); aoff3 = (i0 + 3) * 512;
    asrc0 = Abase + (size_t)r0 * K + (((lane & 7) ^ (r0 & 7)) * 8);
    asrc1 = Abase + (size_t)r1 * K + (((lane & 7) ^ (r1 & 7)) * 8);
    asrc2 = Abase + (size_t)r2 * K + (((lane & 7) ^ (r2 & 7)) * 8);
    asrc3 = Abase + (size_t)r3 * K + (((lane & 7) ^ (r3 & 7)) * 8);
    int j0 = wave * 2;
    int s0 = j0 * 8 + (lane >> 3);       boff0 = BM * BK + j0 * 512;
    int s1 = (j0 + 1) * 8 + (lane >> 3); boff1 = BM * BK + (j0 + 1) * 512;
    bsrc0 = Bbase + (size_t)s0 * K + (((lane & 7) ^ (s0 & 7)) * 8);
    bsrc1 = Bbase + (size_t)s1 * K + (((lane & 7) ^ (s1 & 7)) * 8);
  }

  f32x4 zero4 = {0.f, 0.f, 0.f, 0.f};
  f32x4 acc[4][4];
#pragma unroll
  for (int i = 0; i < 4; ++i)
#pragma unroll
    for (int j = 0; j < 4; ++j) acc[i][j] = zero4;

  int arow[4], brow[4];
#pragma unroll
  for (int t = 0; t < 4; ++t) {
    arow[t] = wm * 64 + t * 16 + l15;   // 0..255
    brow[t] = wn * 64 + t * 16 + l15;   // 0..127
  }

  auto stage_half0 = [&](int kt) {
    bf16_t* slot = lds + (kt % 3) * SLOT;
    int k0 = kt * BK;
    async_copy16(asrc0 + k0, slot + aoff0);
    async_copy16(asrc1 + k0, slot + aoff1);
    async_copy16(bsrc0 + k0, slot + boff0);
  };
  auto stage_half1 = [&](int kt) {
    bf16_t* slot = lds + (kt % 3) * SLOT;
    int k0 = kt * BK;
    async_copy16(asrc2 + k0, slot + aoff2);
    async_copy16(asrc3 + k0, slot + aoff3);
    async_copy16(bsrc1 + k0, slot + boff1);
  };

  stage_half0(0); stage_half1(0);
  stage_half0(1); stage_half1(1);

  for (int kt = 0; kt < NT; ++kt) {
    if (kt + 1 < NT) {
      asm volatile("s_waitcnt vmcnt(6)" ::: "memory");
    } else {
      asm volatile("s_waitcnt vmcnt(0)" ::: "memory");
    }
    __builtin_amdgcn_s_barrier();
    asm volatile("" ::: "memory");

    const bf16_t* As = lds + (kt % 3) * SLOT;
    const bf16_t* Bs = As + BM * BK;
    const bool do_stage = (kt + 2 < NT);

#pragma unroll
    for (int ks = 0; ks < 2; ++ks) {
      if (do_stage) {
        if (ks == 0) stage_half0(kt + 2);
        else         stage_half1(kt + 2);
      }
      bf16x8 af[4], bfv[4];
#pragma unroll
      for (int mt = 0; mt < 4; ++mt)
        af[mt] = *(const bf16x8*)(As + arow[mt] * 64 +
                                  (((ks * 4 + quad) ^ (arow[mt] & 7)) * 8));
#pragma unroll
      for (int nt = 0; nt < 4; ++nt)
        bfv[nt] = *(const bf16x8*)(Bs + brow[nt] * 64 +
                                   (((ks * 4 + quad) ^ (brow[nt] & 7)) * 8));
      __builtin_amdgcn_s_setprio(1);
#pragma unroll
      for (int mt = 0; mt < 4; ++mt)
#pragma unroll
        for (int nt = 0; nt < 4; ++nt)
          acc[mt][nt] = __builtin_amdgcn_mfma_f32_16x16x32_bf16(
              af[mt], bfv[nt], acc[mt][nt], 0, 0, 0);
      __builtin_amdgcn_s_setprio(0);
    }
    __syncthreads();
  }

  float bv[4];
#pragma unroll
  for (int nt = 0; nt < 4; ++nt) bv[nt] = bias[bn * BN + brow[nt]];

#pragma unroll
  for (int mt = 0; mt < 4; ++mt) {
    const int rbase = bm * BM + wm * 64 + mt * 16 + quad * 4;
#pragma unroll
    for (int nt = 0; nt < 4; ++nt) {
      const int col = bn * BN + brow[nt];
      if (out_mode == 0) {
        bf16_t* C = (bf16_t*)Cout;
#pragma unroll
        for (int r = 0; r < 4; ++r)
          C[(size_t)(rbase + r) * N + col] = (bf16_t)((acc[mt][nt][r] + bv[nt]) * scale);
      } else if (out_mode == 2) {
        float* C = (float*)Cout;
#pragma unroll
        for (int r = 0; r < 4; ++r)
          C[(size_t)(rbase + r) * N + col] = acc[mt][nt][r] + bv[nt];
      } else {  // transposed bf16 -> (B, NH, HD, S)
        bf16_t* C = (bf16_t*)Cout;
        const int bb = rbase >> 11;
        const int s0 = rbase & (Sc - 1);
        const int h = col >> 7, d = col & (HDc - 1);
        union { bf16_t h4[4]; uint2 u; } o;
#pragma unroll
        for (int r = 0; r < 4; ++r) o.h4[r] = (bf16_t)(acc[mt][nt][r] + bv[nt]);
        *(uint2*)(C + (((size_t)(bb * NHc + h) * HDc + d) * Sc + s0)) = o.u;
      }
    }
  }
}

// merged Q/K/V projection: blockIdx.y selects which. Saves 2 launch gaps.
__global__ __launch_bounds__(512, 2) void qkv_proj(
    const bf16_t* __restrict__ Xq, const bf16_t* __restrict__ Xk,
    const bf16_t* __restrict__ Xv, const bf16_t* __restrict__ Wq,
    const bf16_t* __restrict__ Wk, const bf16_t* __restrict__ Wv,
    const float* __restrict__ bq, const float* __restrict__ bk,
    const float* __restrict__ bv, bf16_t* __restrict__ q,
    bf16_t* __restrict__ k, bf16_t* __restrict__ vt) {
  const int p = blockIdx.y;
  const bf16_t* A = p == 0 ? Xq : p == 1 ? Xk : Xv;
  const bf16_t* W = p == 0 ? Wq : p == 1 ? Wk : Wv;
  const float* bi = p == 0 ? bq : p == 1 ? bk : bv;
  void* out = p == 0 ? (void*)q : p == 1 ? (void*)k : (void*)vt;
  gemm_body<4096, 2048, 2048>(A, W, bi, out, p == 0 ? SCALE_LOG2E : 1.0f,
                              p == 2 ? 1 : 0);
}

__global__ __launch_bounds__(512, 2) void o_proj(
    const bf16_t* __restrict__ A, const bf16_t* __restrict__ W,
    const float* __restrict__ bi, float* __restrict__ out) {
  gemm_body<4096, 2048, 2048>(A, W, bi, out, 1.0f, 2);
}

// ---------------------------------------------------------------- flash attention
// grid = B*NH*(S/128) = 512; block = 256 (4 waves); 2 blocks/CU.
// KV tiles of 64 keys -> 32 iterations. Wave w owns q-rows [32w,32w+32).
// LDS 67584B: K0 64x128 | K1 64x128 | Vt 128x64 | P 4 x 32 x PSTR.
// R7 schedule: K double-buffered (K[kb+2] issued at end of tile kb); V single-
// buffered, its wait (vmcnt(4)) AFTER QK^T+softmax so V latency hides under
// compute. Softmax exp2-domain (Q pre-scaled); defer-max THR=8; per-lane
// partial-l (epilogue reduce). R10: the 16-lane max shuffle-reduce runs ONLY
// inside the rare rescale branch -- common path is 3 fmax + 1 cmp per row-value
// (lane-local test is exact: rowmax>mrow+8 iff some lane-local max>mrow+8,
// and mrow is row-uniform).
__global__ __launch_bounds__(256, 2) void flash_attn(const bf16_t* __restrict__ Q,
                                                     const bf16_t* __restrict__ Kg,
                                                     const bf16_t* __restrict__ Vt,
                                                     bf16_t* __restrict__ ctx) {
  __shared__ __align__(16) bf16_t smem[2 * 64 * 128 + 128 * 64 + 4 * 32 * PSTR];
  bf16_t* Ks0 = smem;             // K[even] 64x128
  bf16_t* Ks1 = smem + 8192;      // K[odd]  64x128
  bf16_t* Vs = smem + 16384;      // 128 hd x 64 keys (transposed V)
  bf16_t* Ps = smem + 24576;      // per-wave 32 x PSTR

  const int tid = threadIdx.x, lane = tid & 63, wave = tid >> 6;
  const int quad = lane >> 4, l15 = lane & 15;
  const int bid = blockIdx.x;
  const int qt = bid & 15, h = (bid >> 4) & 15, b = bid >> 8;

  bf16_t* Pw = Ps + wave * (32 * PSTR);

  // Q fragments, held in registers for all 32 kv-tiles
  bf16x8 qf[2][4];
#pragma unroll
  for (int mt = 0; mt < 2; ++mt) {
    int grow = b * Sc + qt * 128 + wave * 32 + mt * 16 + l15;
    const bf16_t* qp = Q + (size_t)grow * Hc + h * HDc;
#pragma unroll
    for (int kc = 0; kc < 4; ++kc) qf[mt][kc] = *(const bf16x8*)(qp + kc * 32 + quad * 8);
  }

  f32x4 zero4 = {0.f, 0.f, 0.f, 0.f};
  f32x4 o[2][8];
#pragma unroll
  for (int mt = 0; mt < 2; ++mt)
#pragma unroll
    for (int dt = 0; dt < 8; ++dt) o[mt][dt] = zero4;
  float mrow[2][4], lpart[2][4];
#pragma unroll
  for (int mt = 0; mt < 2; ++mt)
#pragma unroll
    for (int r = 0; r < 4; ++r) { mrow[mt][r] = -1e30f; lpart[mt][r] = 0.f; }

  // staging maps (XOR-swizzled global src, linear LDS dst)
  int kr_[4], kc_[4], vr_[4], vc_[4];
#pragma unroll
  for (int i = 0; i < 4; ++i) {
    int s = wave * 4 + i;
    kr_[i] = s * 4 + quad;        kc_[i] = l15 ^ (kr_[i] & 7);
    vr_[i] = s * 8 + (lane >> 3); vc_[i] = (lane & 7) ^ (vr_[i] & 7);
  }
  const bf16_t* Kbase = Kg + (size_t)b * Sc * Hc + h * HDc;
  const bf16_t* Vbase = Vt + (size_t)(b * NHc + h) * HDc * Sc;

  auto stageK = [&](int kb, bf16_t* dst) {
#pragma unroll
    for (int i = 0; i < 4; ++i)
      async_copy16(Kbase + (size_t)(kb * 64 + kr_[i]) * Hc + kc_[i] * 8,
                   dst + (wave * 4 + i) * 512);
  };
  auto stageV = [&](int kb) {
#pragma unroll
    for (int i = 0; i < 4; ++i)
      async_copy16(Vbase + (size_t)vr_[i] * Sc + kb * 64 + vc_[i] * 8,
                   Vs + (wave * 4 + i) * 512);
  };

  // prologue FIFO: K0(4), V0(4), K1(4)
  stageK(0, Ks0);
  stageV(0);
  stageK(1, Ks1);

  for (int kb = 0; kb < 32; ++kb) {
    bf16_t* Kcur = (kb & 1) ? Ks1 : Ks0;

    // entry: K[kb] landed; V[kb] (4) + K[kb+1] (4) may stay in flight
    if (kb + 1 < 32) asm volatile("s_waitcnt vmcnt(8)" ::: "memory");
    else             asm volatile("s_waitcnt vmcnt(4)" ::: "memory");
    __builtin_amdgcn_s_barrier();
    asm volatile("" ::: "memory");

    // S = Q K^T  (kc outer -> 8 independent MFMA chains)
    f32x4 sf[2][4];
#pragma unroll
    for (int mt = 0; mt < 2; ++mt)
#pragma unroll
      for (int nt = 0; nt < 4; ++nt) sf[mt][nt] = zero4;
#pragma unroll
    for (int kc = 0; kc < 4; ++kc)
#pragma unroll
      for (int nt = 0; nt < 4; ++nt) {
        int kr = nt * 16 + l15;
        bf16x8 kf = *(const bf16x8*)(Kcur + kr * 128 + (((kc * 4 + quad) ^ (kr & 7)) * 8));
        sf[0][nt] = __builtin_amdgcn_mfma_f32_16x16x32_bf16(qf[0][kc], kf, sf[0][nt], 0, 0, 0);
        sf[1][nt] = __builtin_amdgcn_mfma_f32_16x16x32_bf16(qf[1][kc], kf, sf[1][nt], 0, 0, 0);
      }

    // online softmax, exp2 domain. Common path: lane-local threshold only.
    float lmx[2][4];
    bool need = false;
#pragma unroll
    for (int mt = 0; mt < 2; ++mt)
#pragma unroll
      for (int r = 0; r < 4; ++r) {
        float m0 = fmaxf(fmaxf(sf[mt][0][r], sf[mt][1][r]),
                         fmaxf(sf[mt][2][r], sf[mt][3][r]));
        lmx[mt][r] = m0;
        need = need || (m0 > mrow[mt][r] + 8.0f);
      }
    if (__any(need)) {  // rare: full 16-lane reduce + rescale (shuffles only here)
#pragma unroll
      for (int mt = 0; mt < 2; ++mt)
#pragma unroll
        for (int r = 0; r < 4; ++r) {
          float mx = lmx[mt][r];
#pragma unroll
          for (int off = 1; off < 16; off <<= 1) mx = fmaxf(mx, __shfl_xor(mx, off));
          float mnew = fmaxf(mrow[mt][r], mx);
          float alpha = __builtin_amdgcn_exp2f(mrow[mt][r] - mnew);
          mrow[mt][r] = mnew;
          lpart[mt][r] *= alpha;
#pragma unroll
          for (int dt = 0; dt < 8; ++dt) o[mt][dt][r] *= alpha;
        }
    }
#pragma unroll
    for (int mt = 0; mt < 2; ++mt)
#pragma unroll
      for (int r = 0; r < 4; ++r) {
        float p0 = __builtin_amdgcn_exp2f(sf[mt][0][r] - mrow[mt][r]);
        float p1 = __builtin_amdgcn_exp2f(sf[mt][1][r] - mrow[mt][r]);
        float p2 = __builtin_amdgcn_exp2f(sf[mt][2][r] - mrow[mt][r]);
        float p3 = __builtin_amdgcn_exp2f(sf[mt][3][r] - mrow[mt][r]);
        sf[mt][0][r] = p0; sf[mt][1][r] = p1;
        sf[mt][2][r] = p2; sf[mt][3][r] = p3;
        lpart[mt][r] += (p0 + p1) + (p2 + p3);  // per-lane partial; reduce at epilogue
      }

    // P: C-layout regs -> LDS bf16 (wave-private, rows 16B-aligned) -> A-layout frags
#pragma unroll
    for (int mt = 0; mt < 2; ++mt)
#pragma unroll
      for (int nt = 0; nt < 4; ++nt)
#pragma unroll
        for (int r = 0; r < 4; ++r)
          Pw[(mt * 16 + quad * 4 + r) * PSTR + nt * 16 + l15] = (bf16_t)sf[mt][nt][r];

    bf16x8 pf[2][2];
#pragma unroll
    for (int mt = 0; mt < 2; ++mt) {
      const bf16_t* pr = Pw + (mt * 16 + l15) * PSTR;
#pragma unroll
      for (int kc = 0; kc < 2; ++kc)
        pf[mt][kc] = *(const bf16x8*)(pr + kc * 32 + quad * 8);
    }

    // V[kb] landed by now (hidden under QK^T+softmax); K[kb+1] stays in flight
    if (kb + 1 < 32) asm volatile("s_waitcnt vmcnt(4)" ::: "memory");
    else             asm volatile("s_waitcnt vmcnt(0)" ::: "memory");
    __builtin_amdgcn_s_barrier();
    asm volatile("" ::: "memory");

    // O += P V
#pragma unroll
    for (int kc = 0; kc < 2; ++kc)
#pragma unroll
      for (int dt = 0; dt < 8; ++dt) {
        int vr = dt * 16 + l15;
        bf16x8 vf = *(const bf16x8*)(Vs + vr * 64 + (((kc * 4 + quad) ^ (vr & 7)) * 8));
        o[0][dt] = __builtin_amdgcn_mfma_f32_16x16x32_bf16(pf[0][kc], vf, o[0][dt], 0, 0, 0);
        o[1][dt] = __builtin_amdgcn_mfma_f32_16x16x32_bf16(pf[1][kc], vf, o[1][dt], 0, 0, 0);
      }

    __builtin_amdgcn_s_barrier();  // all waves done reading Vs (and Kcur)
    asm volatile("" ::: "memory");
    if (kb + 1 < 32) stageV(kb + 1);
    if (kb + 2 < 32) stageK(kb + 2, Kcur);  // K[kb+2] lives in kb's buffer
  }

  // epilogue: reduce lpart across the 16-lane row group, then O -> smem overlay
  __syncthreads();  // everyone done with Ks/Vs before overlay
  bf16_t* Ow = smem + wave * 4096;  // 32 rows x 128 cols
#pragma unroll
  for (int mt = 0; mt < 2; ++mt) {
    float rinv[4];
#pragma unroll
    for (int r = 0; r < 4; ++r) {
      float l = lpart[mt][r];
#pragma unroll
      for (int off = 1; off < 16; off <<= 1) l += __shfl_xor(l, off);
      rinv[r] = 1.f / l;
    }
#pragma unroll
    for (int dt = 0; dt < 8; ++dt)
#pragma unroll
      for (int r = 0; r < 4; ++r)
        Ow[(mt * 16 + quad * 4 + r) * 128 + dt * 16 + l15] = (bf16_t)(o[mt][dt][r] * rinv[r]);
  }
#pragma unroll
  for (int r = 0; r < 32; ++r) {
    unsigned v = *(const unsigned*)(Ow + r * 128 + lane * 2);
    int grow = b * Sc + qt * 128 + wave * 32 + r;
    *(unsigned*)(ctx + (size_t)grow * Hc + h * HDc + lane * 2) = v;
  }
}

// ---------------------------------------------------------------- launch
extern "C" void kernel_launch(void* const* d_in, const int* in_sizes, int n_in,
                              void* d_out, int out_size, void* d_ws, size_t ws_size,
                              hipStream_t stream) {
  const float* query = (const float*)d_in[0];
  const float* key_i = (const float*)d_in[1];
  const float* value = (const float*)d_in[2];
  const float* Wq = (const float*)d_in[3];
  const float* bq = (const float*)d_in[4];
  const float* Wk = (const float*)d_in[5];
  const float* bk = (const float*)d_in[6];
  const float* Wv = (const float*)d_in[7];
  const float* bv = (const float*)d_in[8];
  const float* Wo = (const float*)d_in[9];
  const float* bo = (const float*)d_in[10];

  const size_t XE = (size_t)Bc * Sc * Hc;  // 8,388,608
  const size_t WE = (size_t)Hc * Hc;       // 4,194,304
  const size_t need = 6 * XE * 2 + 4 * WE * 2;  // 128 MB
  if (ws_size < need) return;

  char* ws = (char*)d_ws;
  size_t off = 0;
  auto alloc = [&](size_t bytes) {
    char* p = ws + off;
    off += (bytes + 255) & ~(size_t)255;
    return p;
  };
  bf16_t* Xq = (bf16_t*)alloc(XE * 2);
  bf16_t* Xk = (bf16_t*)alloc(XE * 2);
  bf16_t* Xv = (bf16_t*)alloc(XE * 2);
  bf16_t* Wqb = (bf16_t*)alloc(WE * 2);
  bf16_t* Wkb = (bf16_t*)alloc(WE * 2);
  bf16_t* Wvb = (bf16_t*)alloc(WE * 2);
  bf16_t* Wob = (bf16_t*)alloc(WE * 2);
  bf16_t* qb = (bf16_t*)alloc(XE * 2);
  bf16_t* kb = (bf16_t*)alloc(XE * 2);
  bf16_t* vtb = (bf16_t*)alloc(XE * 2);
  bf16_t* ctxb = Xq;  // Xq dead after q-projection; reuse for ctx

  cast3<<<dim3((unsigned)(XE / 2048), 3), 256, 0, stream>>>(query, key_i, value, Xq, Xk, Xv);
  cast4<<<dim3((unsigned)(WE / 2048), 4), 256, 0, stream>>>(Wq, Wk, Wv, Wo, Wqb, Wkb, Wvb, Wob);

  qkv_proj<<<dim3(256, 3), 512, 0, stream>>>(Xq, Xk, Xv, Wqb, Wkb, Wvb,
                                             bq, bk, bv, qb, kb, vtb);

  flash_attn<<<512, 256, 0, stream>>>(qb, kb, vtb, ctxb);

  o_proj<<<256, 512, 0, stream>>>(ctxb, Wob, bo, (float*)d_out);
}